// Round 15
// baseline (156.961 us; speedup 1.0000x reference)
//
#include <hip/hip_runtime.h>

#define NQKV_ 384
#define MAGIC_ 0x5CA1AB1E
#define HSTRIDE 140   // h_s row stride (words)
#define QSTRIDE 66    // q_s row stride (words, even -> 8B-aligned float2 reads)
#define KP 33         // kvf row stride in channel-pairs (each pair = 4 floats: k0,k1,v0,v1)

typedef __bf16 bf;
typedef __attribute__((ext_vector_type(4))) __bf16 bf16x4;
typedef __attribute__((ext_vector_type(8))) __bf16 bf16x8;
typedef __attribute__((ext_vector_type(4))) float f32x4;
typedef __attribute__((ext_vector_type(2))) float f32x2;

__device__ __forceinline__ float fast_exp2(float x) {
#if __has_builtin(__builtin_amdgcn_exp2f)
  return __builtin_amdgcn_exp2f(x);
#else
  return exp2f(x);
#endif
}
__device__ __forceinline__ float fast_rcp(float x) {
#if __has_builtin(__builtin_amdgcn_rcpf)
  return __builtin_amdgcn_rcpf(x);
#else
  return 1.0f / x;
#endif
}

// Single persistent kernel. One block per (sequence b, channel-half).
// 256 blocks x 1024 threads (16 waves), ~134 KB LDS -> 1 block/CU.
//
// == r14 lesson (WRITE 40.8->11.1 MB): multi-tile acc arrays held live across
// many MFMAs/phases spill to scratch at the 64-VGPR tier. Keep accumulators
// per-tile and short-lived; keep B-fragments register-resident per Nt run.
// This round applies the same shape to the full GEMM: fused s=0..3 after
// staging (Nt fixed per wave -> 4 B-frags loaded once; per-tile acc +
// immediate bias/relu/residual write). Spin is now unoverlapped -> longer
// busy-poll (pairs are near-lockstep after layer 0). ==
//
// Attention mapping: cp = tid&31 (per-lane channel pair), qg = tid>>5
// (half-wave-uniform query group) -> trans-pipe issue within 1.2% of floor.
// Layer-0 LN computes h = x@in_w+b inline; final out-projection split across
// the pair. All cross-block data via relaxed agent-scope atomics (coherent
// through L3, zero cache maintenance) -> weights stay L2-resident.
__global__ __launch_bounds__(1024)
__attribute__((amdgpu_waves_per_eu(4, 4))) void k_net(
    const float* __restrict__ x, const float* __restrict__ in_w,
    const float* __restrict__ in_b, const float* __restrict__ ln_g,
    const float* __restrict__ ln_b, const float* __restrict__ qkv_w,
    const float* __restrict__ qkv_b, const float* __restrict__ full_w,
    const float* __restrict__ full_b, const float* __restrict__ out_w,
    const float* __restrict__ out_b, bf* __restrict__ wq,
    bf* __restrict__ wf, bf* __restrict__ attg,
    int* __restrict__ flags, int* __restrict__ pflags,
    float* __restrict__ out) {
  __shared__ __align__(16) float h_s[81 * HSTRIDE];   // 45360 B residual (fp32)
  __shared__ __align__(16) bf afrag[96 * 128];        // 24576 B A-fragments, bf16
  __shared__ __align__(16) float q_s[81 * QSTRIDE];   // 21384 B q*log2e (this half)
  __shared__ __align__(16) float kvf[81 * KP * 4];    // 42768 B (k0,k1,v0,v1) per pair

  const int tid = threadIdx.x;
  const int bidx = blockIdx.x;
  const int b = bidx & 127, half = bidx >> 7, c0 = half * 64;
  const int wave = tid >> 6, lane = tid & 63, l15 = lane & 15, quad = lane >> 4;
  const float log2e = 1.4426950408889634f;

  // attg region per block: dense rows [qq][cpair] -> 81*32 u32
  bf* ag_own = attg + (size_t)(b * 2 + half) * 6144;
  const bf* ag_peer = attg + (size_t)(b * 2 + (1 - half)) * 6144;

  // ---- in-kernel weight prep: LDS-staged transpose of one 64x16 subtile ----
  {
    int p = bidx & 127, hp = bidx >> 7;
    int pl = p >> 5, u = p & 31;
    const float* srcw;
    bf* dstt;
    int ldn, n0;
    if (u < 24) {
      srcw = qkv_w + (size_t)pl * 128 * NQKV_;
      dstt = wq + ((size_t)(pl * 24 + u) << 11);
      ldn = NQKV_; n0 = u * 16;
    } else {
      srcw = full_w + (size_t)pl * 128 * 128;
      dstt = wf + ((size_t)(pl * 8 + (u - 24)) << 11);
      ldn = 128; n0 = (u - 24) * 16;
    }
    float (*tile)[17] = reinterpret_cast<float(*)[17]>(h_s);  // alias, pre-LN0
    if (tid < 256) {
      int r = tid >> 2, c4 = (tid & 3) * 4;   // 64 rows x 16 cols, coalesced
      float4 f = *(const float4*)(srcw + (size_t)(hp * 64 + r) * ldn + n0 + c4);
      tile[r][c4 + 0] = f.x; tile[r][c4 + 1] = f.y;
      tile[r][c4 + 2] = f.z; tile[r][c4 + 3] = f.w;
    }
    __syncthreads();
    if (tid < 256) {
      int s_loc = tid >> 7, l = (tid >> 1) & 63, j0 = (tid & 1) * 4;
      int rbase = s_loc * 32 + ((l >> 4) << 3) + j0, col = l & 15;
      unsigned long long pk = 0;
#pragma unroll
      for (int jj = 0; jj < 4; ++jj) {
        bf v = (bf)tile[rbase + jj][col];
        pk |= (unsigned long long)__builtin_bit_cast(unsigned short, v) << (16 * jj);
      }
      __hip_atomic_store((unsigned long long*)(dstt + hp * 1024 + tid * 4), pk,
                         __ATOMIC_RELAXED, __HIP_MEMORY_SCOPE_AGENT);
    }
    __syncthreads();   // tile reads complete (alias freed); stores in flight
    if (tid == 0)
      __hip_atomic_store(&pflags[p * 2 + hp], MAGIC_, __ATOMIC_RELAXED,
                         __HIP_MEMORY_SCOPE_AGENT);
  }

  const float* xb0 = x + (size_t)b * 162;

  for (int layer = 0; layer < 4; ++layer) {
    const bf* wqL = wq + (size_t)layer * 24 * 2048;
    const bf* wfL = wf + (size_t)layer * 8 * 2048;

    // ---- LayerNorm rows -> bf16 A-fragments (single pass).
    //      Layer 0: h = x@in_w+b computed inline, written to h_s. ----
    {
      const float* lg = ln_g + layer * 128;
      const float* lb = ln_b + layer * 128;
      int row = tid >> 3, g8 = tid & 7;
      if (row < 81) {
        float* hr = h_s + row * HSTRIDE;
        float vals[16];
        float sum = 0.f, ssq = 0.f;
        if (layer == 0) {
          float x0 = xb0[row * 2], x1 = xb0[row * 2 + 1];
#pragma unroll
          for (int it = 0; it < 4; ++it) {
            int cc = g8 * 4 + it * 32;
            float4 w0 = *(const float4*)(in_w + cc);
            float4 w1 = *(const float4*)(in_w + 128 + cc);
            float4 b4 = *(const float4*)(in_b + cc);
            float4 f;
            f.x = x0 * w0.x + x1 * w1.x + b4.x;
            f.y = x0 * w0.y + x1 * w1.y + b4.y;
            f.z = x0 * w0.z + x1 * w1.z + b4.z;
            f.w = x0 * w0.w + x1 * w1.w + b4.w;
            *(float4*)(hr + cc) = f;
            vals[it * 4 + 0] = f.x; vals[it * 4 + 1] = f.y;
            vals[it * 4 + 2] = f.z; vals[it * 4 + 3] = f.w;
            sum += f.x + f.y + f.z + f.w;
            ssq += f.x * f.x + f.y * f.y + f.z * f.z + f.w * f.w;
          }
        } else {
#pragma unroll
          for (int it = 0; it < 4; ++it) {
            float4 f = *(const float4*)(hr + g8 * 4 + it * 32);
            vals[it * 4 + 0] = f.x; vals[it * 4 + 1] = f.y;
            vals[it * 4 + 2] = f.z; vals[it * 4 + 3] = f.w;
            sum += f.x + f.y + f.z + f.w;
            ssq += f.x * f.x + f.y * f.y + f.z * f.z + f.w * f.w;
          }
        }
#pragma unroll
        for (int off = 1; off < 8; off <<= 1) {
          sum += __shfl_xor(sum, off);
          ssq += __shfl_xor(ssq, off);
        }
        float mu = sum * (1.f / 128.f);
        float rs = rsqrtf(ssq * (1.f / 128.f) - mu * mu + 1e-5f);
        int mt = row >> 4, m = row & 15;
        int lgp = g8 >> 1, j0 = (g8 & 1) * 4;
#pragma unroll
        for (int it = 0; it < 4; ++it) {
          int cc = g8 * 4 + it * 32;
          float4 gg = *(const float4*)(lg + cc);
          float4 bb = *(const float4*)(lb + cc);
          bf16x4 nv;
          nv[0] = (bf)((vals[it * 4 + 0] - mu) * rs * gg.x + bb.x);
          nv[1] = (bf)((vals[it * 4 + 1] - mu) * rs * gg.y + bb.y);
          nv[2] = (bf)((vals[it * 4 + 2] - mu) * rs * gg.z + bb.z);
          nv[3] = (bf)((vals[it * 4 + 3] - mu) * rs * gg.w + bb.w);
          *(bf16x4*)(afrag + (((mt * 4 + it) * 64 + (lgp * 16 + m)) << 3) + j0) = nv;
        }
      }
    }
    __syncthreads();

    // ---- layer 0 only: wait for all 256 prep units ----
    if (layer == 0) {
      if (wave == 0) {
        long guard = 0;
        for (;;) {
          int ok = 1;
#pragma unroll
          for (int t = 0; t < 4; ++t)
            ok &= (__hip_atomic_load(&pflags[t * 64 + lane], __ATOMIC_RELAXED,
                                     __HIP_MEMORY_SCOPE_AGENT) == MAGIC_);
          if (__all(ok)) break;
          __builtin_amdgcn_s_sleep(2);
          if (++guard > (1L << 24)) break;   // safety valve
        }
      }
      __syncthreads();
      __builtin_amdgcn_fence(__ATOMIC_ACQUIRE, "workgroup");  // ordering only
    }

    // ---- qkv GEMM (half): [96x128] @ [128x192]. Nt-major contiguous tiles:
    //      tau = Nt*6 + Mt; waves 0-7 own [5w,5w+5), waves 8-15 own 4 tiles.
    //      <=2 Nt per wave -> B-fragments register-resident per Nt run. ----
    {
      const float* qb = qkv_b + layer * NQKV_;
      int t0 = (wave < 8) ? wave * 5 : 40 + (wave - 8) * 4;
      int t1 = (wave < 8) ? t0 + 5 : t0 + 4;
      int curNt = -1;
      bf16x8 b0 = {}, b1 = {}, b2 = {}, b3 = {};
      float bias = 0.f;
      int sec = 0, cl = 0;
      for (int tau = t0; tau < t1; ++tau) {
        int Nt = tau / 6, Mt = tau - Nt * 6;
        if (Nt != curNt) {           // wave-uniform branch
          curNt = Nt;
          sec = Nt >> 2;
          int off = Nt & 3;
          int tg = sec * 8 + half * 4 + off;
          const bf* bp = wqL + (size_t)(tg * 4) * 512 + lane * 8;
          b0 = *(const bf16x8*)(bp);
          b1 = *(const bf16x8*)(bp + 512);
          b2 = *(const bf16x8*)(bp + 1024);
          b3 = *(const bf16x8*)(bp + 1536);
          cl = off * 16 + l15;       // 0..63 within half-section
          bias = qb[sec * 128 + c0 + cl];
        }
        f32x4 acc = {};
        bf16x8 a;
        a = *(const bf16x8*)(afrag + (((Mt * 4 + 0) * 64 + lane) << 3));
        acc = __builtin_amdgcn_mfma_f32_16x16x32_bf16(a, b0, acc, 0, 0, 0);
        a = *(const bf16x8*)(afrag + (((Mt * 4 + 1) * 64 + lane) << 3));
        acc = __builtin_amdgcn_mfma_f32_16x16x32_bf16(a, b1, acc, 0, 0, 0);
        a = *(const bf16x8*)(afrag + (((Mt * 4 + 2) * 64 + lane) << 3));
        acc = __builtin_amdgcn_mfma_f32_16x16x32_bf16(a, b2, acc, 0, 0, 0);
        a = *(const bf16x8*)(afrag + (((Mt * 4 + 3) * 64 + lane) << 3));
        acc = __builtin_amdgcn_mfma_f32_16x16x32_bf16(a, b3, acc, 0, 0, 0);
        int Rb = Mt * 16 + quad * 4;
#pragma unroll
        for (int r = 0; r < 4; ++r) {
          int R = Rb + r;
          if (R < 81) {
            float vv = acc[r] + bias;
            if (sec == 0)      q_s[R * QSTRIDE + cl] = vv * log2e;
            else if (sec == 1) kvf[(R * KP + (cl >> 1)) * 4 + (cl & 1)] = vv;
            else               kvf[(R * KP + (cl >> 1)) * 4 + 2 + (cl & 1)] = vv;
          }
        }
      }
    }
    __syncthreads();

    // ---- per-channel attention: lane owns a channel pair (cp = tid&31),
    //      half-wave-uniform query group (qg = tid>>5), float2 packed accums,
    //      stream k,v once ----
    {
      int cp = tid & 31, qg = tid >> 5;        // 32 cpairs x 32 q-groups
      int nq = (qg <= 16) ? 3 : 2;             // qq = qg, qg+32 [, qg+64]
      unsigned int* agc = (unsigned int*)ag_own;
      unsigned int* afu = (unsigned int*)afrag;

      f32x2 xq2[3] = {}, Na2[3] = {}, Da2[3] = {};
#pragma unroll
      for (int j = 0; j < 3; ++j)
        if (j < nq) xq2[j] = *(const f32x2*)(q_s + (qg + 32 * j) * QSTRIDE + 2 * cp);

#pragma unroll 3
      for (int kk = 0; kk < 81; ++kk) {
        float4 kv = *(const float4*)(kvf + (kk * KP + cp) * 4);
        f32x2 k2 = {kv.x, kv.y}, v2 = {kv.z, kv.w};
#pragma unroll
        for (int j = 0; j < 3; ++j) {
          if (j < nq) {
            f32x2 arg = xq2[j] * k2;           // v_pk_mul_f32
            f32x2 e;
            e.x = fast_exp2(arg.x);
            e.y = fast_exp2(arg.y);
            Da2[j] += e;                       // v_pk_add_f32
            Na2[j] += e * v2;                  // v_pk_fma_f32
          }
        }
      }
      int cc = c0 + 2 * cp;
      int sc = cc >> 5, qc = (cc >> 3) & 3, jc = cc & 7;   // jc even
#pragma unroll
      for (int j = 0; j < 3; ++j) {
        if (j < nq) {
          int qq = qg + 32 * j;
          bf b0 = (bf)(Na2[j].x * fast_rcp(Da2[j].x));
          bf b1 = (bf)(Na2[j].y * fast_rcp(Da2[j].y));
          unsigned int packed = (unsigned int)__builtin_bit_cast(unsigned short, b0)
                              | ((unsigned int)__builtin_bit_cast(unsigned short, b1) << 16);
          int m = qq & 15, Mt = qq >> 4;
          afu[(((Mt * 4 + sc) * 512) + qc * 128 + m * 8 + jc) >> 1] = packed;
          __hip_atomic_store(agc + qq * 32 + cp, packed, __ATOMIC_RELAXED,
                             __HIP_MEMORY_SCOPE_AGENT);   // dense 128B rows
        }
      }
    }
    __syncthreads();   // per-wave vmcnt drain: attg stores ack'd at L3

    // ---- publish own att half; spin for peer (unoverlapped: pairs are
    //      near-lockstep after layer 0, so busy-poll long before sleeping) ----
    if (tid == 0) {
      __hip_atomic_store(&flags[bidx * 4 + layer], MAGIC_, __ATOMIC_RELAXED,
                         __HIP_MEMORY_SCOPE_AGENT);
      int peer = (bidx ^ 128) * 4 + layer;
      long guard = 0;
      while (__hip_atomic_load(&flags[peer], __ATOMIC_RELAXED,
                               __HIP_MEMORY_SCOPE_AGENT) != MAGIC_) {
        if (++guard > 4096) __builtin_amdgcn_s_sleep(2);
        if (guard > (1L << 27)) break;   // safety valve vs. hang
      }
    }
    __syncthreads();

    // ---- stage peer att half into afrag: 1296 u64 (81 rows x 16) ----
    {
      const unsigned long long* peer8 = (const unsigned long long*)ag_peer;
      unsigned long long* af8 = (unsigned long long*)afrag;
      int pc0 = 64 - c0;
      for (int t = tid; t < 1296; t += 1024) {
        int qq = t >> 4, cph = t & 15;
        int cc = pc0 + cph * 4;
        int sc = cc >> 5, qc = (cc >> 3) & 3, jc = cc & 7;   // jc in {0,4}
        int m = qq & 15, Mt = qq >> 4;
        unsigned long long v = __hip_atomic_load(peer8 + t, __ATOMIC_RELAXED,
                                                 __HIP_MEMORY_SCOPE_AGENT);
        af8[(((Mt * 4 + sc) * 64 + qc * 16 + m) * 8 + jc) >> 2] = v;
      }
    }
    __syncthreads();

    // ---- full GEMM (fused own+partner, s=0..3): 48 tiles / 16 waves.
    //      Nt = wave&7 fixed -> 4 B-frags loaded once; Mt = (wave>>3)+2i.
    //      Per-tile acc + immediate bias/relu/residual write (r14 shape). ----
    {
      const float* fb = full_b + layer * 128;
      int Nt = wave & 7;
      int col = Nt * 16 + l15;
      float bias = fb[col];
      const bf* bp = wfL + (size_t)(Nt * 4) * 512 + lane * 8;
      bf16x8 b0 = *(const bf16x8*)(bp);
      bf16x8 b1 = *(const bf16x8*)(bp + 512);
      bf16x8 b2 = *(const bf16x8*)(bp + 1024);
      bf16x8 b3 = *(const bf16x8*)(bp + 1536);
#pragma unroll
      for (int i = 0; i < 3; ++i) {
        int Mt = (wave >> 3) + 2 * i;
        f32x4 acc = {};
        bf16x8 a;
        a = *(const bf16x8*)(afrag + (((Mt * 4 + 0) * 64 + lane) << 3));
        acc = __builtin_amdgcn_mfma_f32_16x16x32_bf16(a, b0, acc, 0, 0, 0);
        a = *(const bf16x8*)(afrag + (((Mt * 4 + 1) * 64 + lane) << 3));
        acc = __builtin_amdgcn_mfma_f32_16x16x32_bf16(a, b1, acc, 0, 0, 0);
        a = *(const bf16x8*)(afrag + (((Mt * 4 + 2) * 64 + lane) << 3));
        acc = __builtin_amdgcn_mfma_f32_16x16x32_bf16(a, b2, acc, 0, 0, 0);
        a = *(const bf16x8*)(afrag + (((Mt * 4 + 3) * 64 + lane) << 3));
        acc = __builtin_amdgcn_mfma_f32_16x16x32_bf16(a, b3, acc, 0, 0, 0);
        int Rb = Mt * 16 + quad * 4;
#pragma unroll
        for (int r = 0; r < 4; ++r) {
          int R = Rb + r;
          if (R < 81) h_s[R * HSTRIDE + col] += fmaxf(acc[r] + bias, 0.f);
        }
      }
    }
    __syncthreads();
  }

  // ---- out = h @ out_w + out_b: split across the pair (both hold full h_s).
  //      half 0: rows 0..40, half 1: rows 41..80 ----
  {
    int nrows = 41 - half;           // 41 or 40
    int row = tid >> 3, g8 = tid & 7;
    if (row < nrows) {
      int grow = half * 41 + row;
      const float* hr = h_s + grow * HSTRIDE;
      float o0 = 0.f, o1 = 0.f, o2 = 0.f, o3 = 0.f;
#pragma unroll
      for (int it = 0; it < 4; ++it) {
        int cc = g8 * 4 + it * 32;
        float4 f = *(const float4*)(hr + cc);
        float4 wA = *(const float4*)(out_w + (cc + 0) * 4);
        float4 wB = *(const float4*)(out_w + (cc + 1) * 4);
        float4 wC = *(const float4*)(out_w + (cc + 2) * 4);
        float4 wD = *(const float4*)(out_w + (cc + 3) * 4);
        o0 += f.x * wA.x + f.y * wB.x + f.z * wC.x + f.w * wD.x;
        o1 += f.x * wA.y + f.y * wB.y + f.z * wC.y + f.w * wD.y;
        o2 += f.x * wA.z + f.y * wB.z + f.z * wC.z + f.w * wD.z;
        o3 += f.x * wA.w + f.y * wB.w + f.z * wC.w + f.w * wD.w;
      }
#pragma unroll
      for (int off = 1; off < 8; off <<= 1) {
        o0 += __shfl_xor(o0, off); o1 += __shfl_xor(o1, off);
        o2 += __shfl_xor(o2, off); o3 += __shfl_xor(o3, off);
      }
      if (g8 == 0) {
        *(float4*)(out + ((size_t)b * 81 + grow) * 4) =
            make_float4(o0 + out_b[0], o1 + out_b[1], o2 + out_b[2], o3 + out_b[3]);
      }
    }
  }
}

extern "C" void kernel_launch(void* const* d_in, const int* in_sizes, int n_in,
                              void* d_out, int out_size, void* d_ws, size_t ws_size,
                              hipStream_t stream) {
  const float* x      = (const float*)d_in[0];
  const float* in_w   = (const float*)d_in[1];
  const float* in_b   = (const float*)d_in[2];
  const float* ln_g   = (const float*)d_in[3];
  const float* ln_b   = (const float*)d_in[4];
  const float* qkv_w  = (const float*)d_in[5];
  const float* qkv_b  = (const float*)d_in[6];
  const float* full_w = (const float*)d_in[7];
  const float* full_b = (const float*)d_in[8];
  const float* out_w  = (const float*)d_in[9];
  const float* out_b  = (const float*)d_in[10];

  bf* wq      = (bf*)d_ws;                 // 196608 bf16
  bf* wf      = wq + 196608;               // 65536 bf16
  bf* attg    = wf + 65536;                // 256*6144 bf16 ([qq][cpair] u32 rows)
  int* flags  = (int*)(attg + 1572864);    // 256*4 exchange flags (poisoned each launch)
  int* pflags = flags + 1024;              // 256 prep flags (poisoned each launch)
  float* out  = (float*)d_out;

  k_net<<<256, 1024, 0, stream>>>(x, in_w, in_b, ln_g, ln_b, qkv_w, qkv_b,
                                  full_w, full_b, out_w, out_b, wq, wf, attg,
                                  flags, pflags, out);
}

// Round 16
// 155.081 us; speedup vs baseline: 1.0121x; 1.0121x over previous
//
#include <hip/hip_runtime.h>

#define NQKV_ 384
#define MAGIC_ 0x5CA1AB1E
#define HSTRIDE 140   // h_s row stride (words)
#define QSTRIDE 66    // q_s row stride (words, even -> 8B-aligned float2 reads)
#define KP 33         // kvf row stride in channel-pairs (each pair = 4 floats: k0,k1,v0,v1)

typedef __bf16 bf;
typedef __attribute__((ext_vector_type(4))) __bf16 bf16x4;
typedef __attribute__((ext_vector_type(8))) __bf16 bf16x8;
typedef __attribute__((ext_vector_type(4))) float f32x4;
typedef __attribute__((ext_vector_type(2))) float f32x2;

__device__ __forceinline__ float fast_exp2(float x) {
#if __has_builtin(__builtin_amdgcn_exp2f)
  return __builtin_amdgcn_exp2f(x);
#else
  return exp2f(x);
#endif
}
__device__ __forceinline__ float fast_rcp(float x) {
#if __has_builtin(__builtin_amdgcn_rcpf)
  return __builtin_amdgcn_rcpf(x);
#else
  return 1.0f / x;
#endif
}

// Single persistent kernel. One block per (sequence b, channel-half).
// 256 blocks x 1024 threads (16 waves), ~134 KB LDS -> 1 block/CU.
// == SESSION-BEST FORM (round 14, k_net 96.0 us / bench 155.2 us). ==
//
// Key structural facts (each backed by a counter experiment):
// - qkv GEMM: Nt-major contiguous tiles (tau = Nt*6+Mt; <=2 Nt per wave),
//   B-fragments register-resident per Nt run, PER-TILE short-lived acc.
//   The old 5-way interleaved acc[5] silently spilled to scratch at the
//   64-VGPR tier (WRITE 40.8 -> 11.1 MB when fixed). Do not re-introduce
//   wide live accumulator arrays.
// - full GEMM: own-half acc[3] overlaps the peer-flag spin (r15 showed
//   unoverlapped fused form is ~1.3 us slower; acc[3] does NOT spill).
// - Attention: cp = tid&31 (per-lane channel pair), qg = tid>>5 (half-wave-
//   uniform query group) -> trans-pipe issue within 1.2% of the ~22 us
//   exp2 floor. Per-lane qg variants cost +19% trans issue (r8/r9).
//   Do not hand-pipeline the kv loop (r12: compiler already optimal).
// - All cross-block data via relaxed agent-scope atomics (coherent through
//   L3, ZERO cache maintenance anywhere) -> weights stay L2-resident.
//   Flag publishes relaxed: preceding __syncthreads drains vmcnt per wave.
// - Layer-0 LN computes h = x@in_w+b inline; out-projection split across
//   the pair; weight prep in-kernel via LDS-staged transpose.
__global__ __launch_bounds__(1024)
__attribute__((amdgpu_waves_per_eu(4, 4))) void k_net(
    const float* __restrict__ x, const float* __restrict__ in_w,
    const float* __restrict__ in_b, const float* __restrict__ ln_g,
    const float* __restrict__ ln_b, const float* __restrict__ qkv_w,
    const float* __restrict__ qkv_b, const float* __restrict__ full_w,
    const float* __restrict__ full_b, const float* __restrict__ out_w,
    const float* __restrict__ out_b, bf* __restrict__ wq,
    bf* __restrict__ wf, bf* __restrict__ attg,
    int* __restrict__ flags, int* __restrict__ pflags,
    float* __restrict__ out) {
  __shared__ __align__(16) float h_s[81 * HSTRIDE];   // 45360 B residual (fp32)
  __shared__ __align__(16) bf afrag[96 * 128];        // 24576 B A-fragments, bf16
  __shared__ __align__(16) float q_s[81 * QSTRIDE];   // 21384 B q*log2e (this half)
  __shared__ __align__(16) float kvf[81 * KP * 4];    // 42768 B (k0,k1,v0,v1) per pair

  const int tid = threadIdx.x;
  const int bidx = blockIdx.x;
  const int b = bidx & 127, half = bidx >> 7, c0 = half * 64;
  const int wave = tid >> 6, lane = tid & 63, l15 = lane & 15, quad = lane >> 4;
  const float log2e = 1.4426950408889634f;

  // attg region per block: dense rows [qq][cpair] -> 81*32 u32
  bf* ag_own = attg + (size_t)(b * 2 + half) * 6144;
  const bf* ag_peer = attg + (size_t)(b * 2 + (1 - half)) * 6144;

  // ---- in-kernel weight prep: LDS-staged transpose of one 64x16 subtile ----
  {
    int p = bidx & 127, hp = bidx >> 7;
    int pl = p >> 5, u = p & 31;
    const float* srcw;
    bf* dstt;
    int ldn, n0;
    if (u < 24) {
      srcw = qkv_w + (size_t)pl * 128 * NQKV_;
      dstt = wq + ((size_t)(pl * 24 + u) << 11);
      ldn = NQKV_; n0 = u * 16;
    } else {
      srcw = full_w + (size_t)pl * 128 * 128;
      dstt = wf + ((size_t)(pl * 8 + (u - 24)) << 11);
      ldn = 128; n0 = (u - 24) * 16;
    }
    float (*tile)[17] = reinterpret_cast<float(*)[17]>(h_s);  // alias, pre-LN0
    if (tid < 256) {
      int r = tid >> 2, c4 = (tid & 3) * 4;   // 64 rows x 16 cols, coalesced
      float4 f = *(const float4*)(srcw + (size_t)(hp * 64 + r) * ldn + n0 + c4);
      tile[r][c4 + 0] = f.x; tile[r][c4 + 1] = f.y;
      tile[r][c4 + 2] = f.z; tile[r][c4 + 3] = f.w;
    }
    __syncthreads();
    if (tid < 256) {
      int s_loc = tid >> 7, l = (tid >> 1) & 63, j0 = (tid & 1) * 4;
      int rbase = s_loc * 32 + ((l >> 4) << 3) + j0, col = l & 15;
      unsigned long long pk = 0;
#pragma unroll
      for (int jj = 0; jj < 4; ++jj) {
        bf v = (bf)tile[rbase + jj][col];
        pk |= (unsigned long long)__builtin_bit_cast(unsigned short, v) << (16 * jj);
      }
      __hip_atomic_store((unsigned long long*)(dstt + hp * 1024 + tid * 4), pk,
                         __ATOMIC_RELAXED, __HIP_MEMORY_SCOPE_AGENT);
    }
    __syncthreads();   // tile reads complete (alias freed); stores in flight
    if (tid == 0)
      __hip_atomic_store(&pflags[p * 2 + hp], MAGIC_, __ATOMIC_RELAXED,
                         __HIP_MEMORY_SCOPE_AGENT);
  }

  const float* xb0 = x + (size_t)b * 162;

  for (int layer = 0; layer < 4; ++layer) {
    const bf* wqL = wq + (size_t)layer * 24 * 2048;
    const bf* wfL = wf + (size_t)layer * 8 * 2048;

    // ---- LayerNorm rows -> bf16 A-fragments (single pass).
    //      Layer 0: h = x@in_w+b computed inline, written to h_s. ----
    {
      const float* lg = ln_g + layer * 128;
      const float* lb = ln_b + layer * 128;
      int row = tid >> 3, g8 = tid & 7;
      if (row < 81) {
        float* hr = h_s + row * HSTRIDE;
        float vals[16];
        float sum = 0.f, ssq = 0.f;
        if (layer == 0) {
          float x0 = xb0[row * 2], x1 = xb0[row * 2 + 1];
#pragma unroll
          for (int it = 0; it < 4; ++it) {
            int cc = g8 * 4 + it * 32;
            float4 w0 = *(const float4*)(in_w + cc);
            float4 w1 = *(const float4*)(in_w + 128 + cc);
            float4 b4 = *(const float4*)(in_b + cc);
            float4 f;
            f.x = x0 * w0.x + x1 * w1.x + b4.x;
            f.y = x0 * w0.y + x1 * w1.y + b4.y;
            f.z = x0 * w0.z + x1 * w1.z + b4.z;
            f.w = x0 * w0.w + x1 * w1.w + b4.w;
            *(float4*)(hr + cc) = f;
            vals[it * 4 + 0] = f.x; vals[it * 4 + 1] = f.y;
            vals[it * 4 + 2] = f.z; vals[it * 4 + 3] = f.w;
            sum += f.x + f.y + f.z + f.w;
            ssq += f.x * f.x + f.y * f.y + f.z * f.z + f.w * f.w;
          }
        } else {
#pragma unroll
          for (int it = 0; it < 4; ++it) {
            float4 f = *(const float4*)(hr + g8 * 4 + it * 32);
            vals[it * 4 + 0] = f.x; vals[it * 4 + 1] = f.y;
            vals[it * 4 + 2] = f.z; vals[it * 4 + 3] = f.w;
            sum += f.x + f.y + f.z + f.w;
            ssq += f.x * f.x + f.y * f.y + f.z * f.z + f.w * f.w;
          }
        }
#pragma unroll
        for (int off = 1; off < 8; off <<= 1) {
          sum += __shfl_xor(sum, off);
          ssq += __shfl_xor(ssq, off);
        }
        float mu = sum * (1.f / 128.f);
        float rs = rsqrtf(ssq * (1.f / 128.f) - mu * mu + 1e-5f);
        int mt = row >> 4, m = row & 15;
        int lgp = g8 >> 1, j0 = (g8 & 1) * 4;
#pragma unroll
        for (int it = 0; it < 4; ++it) {
          int cc = g8 * 4 + it * 32;
          float4 gg = *(const float4*)(lg + cc);
          float4 bb = *(const float4*)(lb + cc);
          bf16x4 nv;
          nv[0] = (bf)((vals[it * 4 + 0] - mu) * rs * gg.x + bb.x);
          nv[1] = (bf)((vals[it * 4 + 1] - mu) * rs * gg.y + bb.y);
          nv[2] = (bf)((vals[it * 4 + 2] - mu) * rs * gg.z + bb.z);
          nv[3] = (bf)((vals[it * 4 + 3] - mu) * rs * gg.w + bb.w);
          *(bf16x4*)(afrag + (((mt * 4 + it) * 64 + (lgp * 16 + m)) << 3) + j0) = nv;
        }
      }
    }
    __syncthreads();

    // ---- layer 0 only: wait for all 256 prep units ----
    if (layer == 0) {
      if (wave == 0) {
        long guard = 0;
        for (;;) {
          int ok = 1;
#pragma unroll
          for (int t = 0; t < 4; ++t)
            ok &= (__hip_atomic_load(&pflags[t * 64 + lane], __ATOMIC_RELAXED,
                                     __HIP_MEMORY_SCOPE_AGENT) == MAGIC_);
          if (__all(ok)) break;
          __builtin_amdgcn_s_sleep(2);
          if (++guard > (1L << 24)) break;   // safety valve
        }
      }
      __syncthreads();
      __builtin_amdgcn_fence(__ATOMIC_ACQUIRE, "workgroup");  // ordering only
    }

    // ---- qkv GEMM (half): [96x128] @ [128x192]. Nt-major contiguous tiles:
    //      tau = Nt*6 + Mt; waves 0-7 own [5w,5w+5), waves 8-15 own 4 tiles.
    //      <=2 Nt per wave -> B-fragments register-resident per Nt run. ----
    {
      const float* qb = qkv_b + layer * NQKV_;
      int t0 = (wave < 8) ? wave * 5 : 40 + (wave - 8) * 4;
      int t1 = (wave < 8) ? t0 + 5 : t0 + 4;
      int curNt = -1;
      bf16x8 b0 = {}, b1 = {}, b2 = {}, b3 = {};
      float bias = 0.f;
      int sec = 0, cl = 0;
      for (int tau = t0; tau < t1; ++tau) {
        int Nt = tau / 6, Mt = tau - Nt * 6;
        if (Nt != curNt) {           // wave-uniform branch
          curNt = Nt;
          sec = Nt >> 2;
          int off = Nt & 3;
          int tg = sec * 8 + half * 4 + off;
          const bf* bp = wqL + (size_t)(tg * 4) * 512 + lane * 8;
          b0 = *(const bf16x8*)(bp);
          b1 = *(const bf16x8*)(bp + 512);
          b2 = *(const bf16x8*)(bp + 1024);
          b3 = *(const bf16x8*)(bp + 1536);
          cl = off * 16 + l15;       // 0..63 within half-section
          bias = qb[sec * 128 + c0 + cl];
        }
        f32x4 acc = {};
        bf16x8 a;
        a = *(const bf16x8*)(afrag + (((Mt * 4 + 0) * 64 + lane) << 3));
        acc = __builtin_amdgcn_mfma_f32_16x16x32_bf16(a, b0, acc, 0, 0, 0);
        a = *(const bf16x8*)(afrag + (((Mt * 4 + 1) * 64 + lane) << 3));
        acc = __builtin_amdgcn_mfma_f32_16x16x32_bf16(a, b1, acc, 0, 0, 0);
        a = *(const bf16x8*)(afrag + (((Mt * 4 + 2) * 64 + lane) << 3));
        acc = __builtin_amdgcn_mfma_f32_16x16x32_bf16(a, b2, acc, 0, 0, 0);
        a = *(const bf16x8*)(afrag + (((Mt * 4 + 3) * 64 + lane) << 3));
        acc = __builtin_amdgcn_mfma_f32_16x16x32_bf16(a, b3, acc, 0, 0, 0);
        int Rb = Mt * 16 + quad * 4;
#pragma unroll
        for (int r = 0; r < 4; ++r) {
          int R = Rb + r;
          if (R < 81) {
            float vv = acc[r] + bias;
            if (sec == 0)      q_s[R * QSTRIDE + cl] = vv * log2e;
            else if (sec == 1) kvf[(R * KP + (cl >> 1)) * 4 + (cl & 1)] = vv;
            else               kvf[(R * KP + (cl >> 1)) * 4 + 2 + (cl & 1)] = vv;
          }
        }
      }
    }
    __syncthreads();

    // ---- per-channel attention: lane owns a channel pair (cp = tid&31),
    //      half-wave-uniform query group (qg = tid>>5), float2 packed accums,
    //      stream k,v once ----
    {
      int cp = tid & 31, qg = tid >> 5;        // 32 cpairs x 32 q-groups
      int nq = (qg <= 16) ? 3 : 2;             // qq = qg, qg+32 [, qg+64]
      unsigned int* agc = (unsigned int*)ag_own;
      unsigned int* afu = (unsigned int*)afrag;

      f32x2 xq2[3] = {}, Na2[3] = {}, Da2[3] = {};
#pragma unroll
      for (int j = 0; j < 3; ++j)
        if (j < nq) xq2[j] = *(const f32x2*)(q_s + (qg + 32 * j) * QSTRIDE + 2 * cp);

#pragma unroll 3
      for (int kk = 0; kk < 81; ++kk) {
        float4 kv = *(const float4*)(kvf + (kk * KP + cp) * 4);
        f32x2 k2 = {kv.x, kv.y}, v2 = {kv.z, kv.w};
#pragma unroll
        for (int j = 0; j < 3; ++j) {
          if (j < nq) {
            f32x2 arg = xq2[j] * k2;           // v_pk_mul_f32
            f32x2 e;
            e.x = fast_exp2(arg.x);
            e.y = fast_exp2(arg.y);
            Da2[j] += e;                       // v_pk_add_f32
            Na2[j] += e * v2;                  // v_pk_fma_f32
          }
        }
      }
      int cc = c0 + 2 * cp;
      int sc = cc >> 5, qc = (cc >> 3) & 3, jc = cc & 7;   // jc even
#pragma unroll
      for (int j = 0; j < 3; ++j) {
        if (j < nq) {
          int qq = qg + 32 * j;
          bf b0 = (bf)(Na2[j].x * fast_rcp(Da2[j].x));
          bf b1 = (bf)(Na2[j].y * fast_rcp(Da2[j].y));
          unsigned int packed = (unsigned int)__builtin_bit_cast(unsigned short, b0)
                              | ((unsigned int)__builtin_bit_cast(unsigned short, b1) << 16);
          int m = qq & 15, Mt = qq >> 4;
          afu[(((Mt * 4 + sc) * 512) + qc * 128 + m * 8 + jc) >> 1] = packed;
          __hip_atomic_store(agc + qq * 32 + cp, packed, __ATOMIC_RELAXED,
                             __HIP_MEMORY_SCOPE_AGENT);   // dense 128B rows
        }
      }
    }
    __syncthreads();   // per-wave vmcnt drain: attg stores ack'd at L3

    // ---- publish own att half (relaxed; ordered by barrier drain) ----
    if (tid == 0) {
      __hip_atomic_store(&flags[bidx * 4 + layer], MAGIC_, __ATOMIC_RELAXED,
                         __HIP_MEMORY_SCOPE_AGENT);
    }
    f32x4 acc[3] = {};
    {
      int sbase = half * 2;          // own channels: s in {2*half, 2*half+1}
#pragma unroll
      for (int i = 0; i < 3; ++i) {
        int tau = wave + 16 * i;
        int Mt = tau >> 3, Nt = tau & 7;
#pragma unroll
        for (int ss = 0; ss < 2; ++ss) {
          int s = sbase + ss;
          bf16x8 a = *(const bf16x8*)(afrag + (((Mt * 4 + s) * 64 + lane) << 3));
          bf16x8 bb = *(const bf16x8*)(wfL + ((Nt * 4 + s) * 512 + lane * 8));
          acc[i] = __builtin_amdgcn_mfma_f32_16x16x32_bf16(a, bb, acc[i], 0, 0, 0);
        }
      }
    }
    // Relaxed spin: brief busy-poll (catches small pair skew at full speed),
    // then sleep-poll. No fence (data travels via coherent atomics).
    if (tid == 0) {
      int peer = (bidx ^ 128) * 4 + layer;
      long guard = 0;
      while (__hip_atomic_load(&flags[peer], __ATOMIC_RELAXED,
                               __HIP_MEMORY_SCOPE_AGENT) != MAGIC_) {
        if (++guard > 64) __builtin_amdgcn_s_sleep(2);
        if (guard > (1L << 27)) break;   // safety valve vs. hang
      }
    }
    __syncthreads();

    // ---- stage peer att half into afrag: 1296 u64 (81 rows x 16) ----
    {
      const unsigned long long* peer8 = (const unsigned long long*)ag_peer;
      unsigned long long* af8 = (unsigned long long*)afrag;
      int pc0 = 64 - c0;
      for (int t = tid; t < 1296; t += 1024) {
        int qq = t >> 4, cph = t & 15;
        int cc = pc0 + cph * 4;
        int sc = cc >> 5, qc = (cc >> 3) & 3, jc = cc & 7;   // jc in {0,4}
        int m = qq & 15, Mt = qq >> 4;
        unsigned long long v = __hip_atomic_load(peer8 + t, __ATOMIC_RELAXED,
                                                 __HIP_MEMORY_SCOPE_AGENT);
        af8[(((Mt * 4 + sc) * 64 + qc * 16 + m) * 8 + jc) >> 2] = v;
      }
    }
    __syncthreads();

    // ---- partner-half K-chunks + bias + relu + residual into h_s ----
    {
      int pbase = 2 - half * 2;      // partner channels
#pragma unroll
      for (int i = 0; i < 3; ++i) {
        int tau = wave + 16 * i;
        int Mt = tau >> 3, Nt = tau & 7;
#pragma unroll
        for (int ss = 0; ss < 2; ++ss) {
          int s = pbase + ss;
          bf16x8 a = *(const bf16x8*)(afrag + (((Mt * 4 + s) * 64 + lane) << 3));
          bf16x8 bb = *(const bf16x8*)(wfL + ((Nt * 4 + s) * 512 + lane * 8));
          acc[i] = __builtin_amdgcn_mfma_f32_16x16x32_bf16(a, bb, acc[i], 0, 0, 0);
        }
      }
      const float* fb = full_b + layer * 128;
#pragma unroll
      for (int i = 0; i < 3; ++i) {
        int tau = wave + 16 * i;
        int Mt = tau >> 3, Nt = tau & 7;
        int col = Nt * 16 + l15;
        float bias = fb[col];
        int Rb = Mt * 16 + quad * 4;
#pragma unroll
        for (int r = 0; r < 4; ++r) {
          int R = Rb + r;
          if (R < 81) h_s[R * HSTRIDE + col] += fmaxf(acc[i][r] + bias, 0.f);
        }
      }
    }
    __syncthreads();
  }

  // ---- out = h @ out_w + out_b: split across the pair (both hold full h_s).
  //      half 0: rows 0..40, half 1: rows 41..80 ----
  {
    int nrows = 41 - half;           // 41 or 40
    int row = tid >> 3, g8 = tid & 7;
    if (row < nrows) {
      int grow = half * 41 + row;
      const float* hr = h_s + grow * HSTRIDE;
      float o0 = 0.f, o1 = 0.f, o2 = 0.f, o3 = 0.f;
#pragma unroll
      for (int it = 0; it < 4; ++it) {
        int cc = g8 * 4 + it * 32;
        float4 f = *(const float4*)(hr + cc);
        float4 wA = *(const float4*)(out_w + (cc + 0) * 4);
        float4 wB = *(const float4*)(out_w + (cc + 1) * 4);
        float4 wC = *(const float4*)(out_w + (cc + 2) * 4);
        float4 wD = *(const float4*)(out_w + (cc + 3) * 4);
        o0 += f.x * wA.x + f.y * wB.x + f.z * wC.x + f.w * wD.x;
        o1 += f.x * wA.y + f.y * wB.y + f.z * wC.y + f.w * wD.y;
        o2 += f.x * wA.z + f.y * wB.z + f.z * wC.z + f.w * wD.z;
        o3 += f.x * wA.w + f.y * wB.w + f.z * wC.w + f.w * wD.w;
      }
#pragma unroll
      for (int off = 1; off < 8; off <<= 1) {
        o0 += __shfl_xor(o0, off); o1 += __shfl_xor(o1, off);
        o2 += __shfl_xor(o2, off); o3 += __shfl_xor(o3, off);
      }
      if (g8 == 0) {
        *(float4*)(out + ((size_t)b * 81 + grow) * 4) =
            make_float4(o0 + out_b[0], o1 + out_b[1], o2 + out_b[2], o3 + out_b[3]);
      }
    }
  }
}

extern "C" void kernel_launch(void* const* d_in, const int* in_sizes, int n_in,
                              void* d_out, int out_size, void* d_ws, size_t ws_size,
                              hipStream_t stream) {
  const float* x      = (const float*)d_in[0];
  const float* in_w   = (const float*)d_in[1];
  const float* in_b   = (const float*)d_in[2];
  const float* ln_g   = (const float*)d_in[3];
  const float* ln_b   = (const float*)d_in[4];
  const float* qkv_w  = (const float*)d_in[5];
  const float* qkv_b  = (const float*)d_in[6];
  const float* full_w = (const float*)d_in[7];
  const float* full_b = (const float*)d_in[8];
  const float* out_w  = (const float*)d_in[9];
  const float* out_b  = (const float*)d_in[10];

  bf* wq      = (bf*)d_ws;                 // 196608 bf16
  bf* wf      = wq + 196608;               // 65536 bf16
  bf* attg    = wf + 65536;                // 256*6144 bf16 ([qq][cpair] u32 rows)
  int* flags  = (int*)(attg + 1572864);    // 256*4 exchange flags (poisoned each launch)
  int* pflags = flags + 1024;              // 256 prep flags (poisoned each launch)
  float* out  = (float*)d_out;

  k_net<<<256, 1024, 0, stream>>>(x, in_w, in_b, ln_g, ln_b, qkv_w, qkv_b,
                                  full_w, full_b, out_w, out_b, wq, wf, attg,
                                  flags, pflags, out);
}